// Round 1
// baseline (1403.737 us; speedup 1.0000x reference)
//
#include <hip/hip_runtime.h>
#include <hip/hip_bf16.h>

#define NN 10000
#define EE 160000
#define CC 512
#define HH 4
#define RR 8
#define LL 2
#define EDD 768
#define OO 128   // CC/HH

typedef __attribute__((ext_vector_type(8))) short bf16x8;
typedef __attribute__((ext_vector_type(4))) float f32x4;

// ---------------- CSR build ----------------
__global__ void trg_hist(const int* __restrict__ ei, int* __restrict__ deg) {
  int e = blockIdx.x * 256 + threadIdx.x;
  if (e < EE) atomicAdd(&deg[ei[EE + e]], 1);
}

__global__ void trg_scan(const int* __restrict__ deg, int* __restrict__ offs,
                         int* __restrict__ cursor) {
  __shared__ int sp[256];
  int t = threadIdx.x;
  const int CHK = (NN + 255) / 256;
  int lo = t * CHK, hi = lo + CHK; if (hi > NN) hi = NN; if (lo > NN) lo = NN;
  int s = 0;
  for (int i = lo; i < hi; i++) s += deg[i];
  sp[t] = s;
  __syncthreads();
  if (t == 0) {
    int run = 0;
    for (int i = 0; i < 256; i++) { int v = sp[i]; sp[i] = run; run += v; }
  }
  __syncthreads();
  int run = sp[t];
  for (int i = lo; i < hi; i++) { offs[i] = run; cursor[i] = run; run += deg[i]; }
  if (t == 255) offs[NN] = run;
}

__global__ void trg_fill(const int* __restrict__ ei, int* __restrict__ cursor,
                         int* __restrict__ elist) {
  int e = blockIdx.x * 256 + threadIdx.x;
  if (e < EE) {
    int pos = atomicAdd(&cursor[ei[EE + e]], 1);
    elist[pos] = e;
  }
}

// ---------------- conversions ----------------
// transpose f32 [P][Q] (+z*inStride) -> bf16 [Q][P] (+z*outStride)
__global__ void trg_transpose(const float* __restrict__ in, __hip_bfloat16* __restrict__ out,
                              int P, int Q, long inStride, long outStride) {
  __shared__ float tile[32][33];
  int z = blockIdx.z;
  const float* inz = in + (long)z * inStride;
  __hip_bfloat16* outz = out + (long)z * outStride;
  int q0 = blockIdx.x * 32, p0 = blockIdx.y * 32;
  int tx = threadIdx.x, ty = threadIdx.y;
#pragma unroll
  for (int i = 0; i < 4; i++)
    tile[ty + i * 8][tx] = inz[(long)(p0 + ty + i * 8) * Q + q0 + tx];
  __syncthreads();
#pragma unroll
  for (int i = 0; i < 4; i++)
    outz[(long)(q0 + ty + i * 8) * P + p0 + tx] = __float2bfloat16(tile[tx][ty + i * 8]);
}

__global__ void trg_cast_bf16(const float* __restrict__ in, __hip_bfloat16* __restrict__ out, int n4) {
  int i = blockIdx.x * 256 + threadIdx.x;
  if (i >= n4) return;
  float4 v = ((const float4*)in)[i];
  union { ushort4 u; __hip_bfloat16 h[4]; } cv;
  cv.h[0] = __float2bfloat16(v.x); cv.h[1] = __float2bfloat16(v.y);
  cv.h[2] = __float2bfloat16(v.z); cv.h[3] = __float2bfloat16(v.w);
  ((ushort4*)out)[i] = cv.u;
}

// ---------------- small precomputes ----------------
// Me[l][ed][h] = sum_c w_edge[l][ed][c] * e[l][c][h]
__global__ void trg_me(const float* __restrict__ we, const float* __restrict__ ep,
                       float* __restrict__ Me) {
  int idx = blockIdx.x * 256 + threadIdx.x;
  if (idx >= LL * EDD * HH) return;
  int l = idx / (EDD * HH);
  int r = idx % (EDD * HH);
  int ed = r / HH, h = r % HH;
  const float* wr = we + ((long)l * EDD + ed) * CC;
  const float* ec = ep + (long)l * CC * HH + h;
  float acc = 0.f;
  for (int c = 0; c < CC; c++) acc += wr[c] * ec[c * HH];
  Me[idx] = acc;
}

// qcat[l][c][j]: j<4 -> q[l][c][j], else k[l][c][j-4]
__global__ void trg_qcat(const float* __restrict__ qp, const float* __restrict__ kp,
                         float* __restrict__ qcat) {
  int idx = blockIdx.x * 256 + threadIdx.x;
  if (idx >= LL * CC * 8) return;
  int l = idx / (CC * 8);
  int r = idx % (CC * 8);
  int c = r >> 3, j = r & 7;
  qcat[idx] = (j < 4) ? qp[((long)l * CC + c) * HH + j]
                      : kp[((long)l * CC + c) * HH + (j - 4)];
}

// AE[e][l*4+h] = eattr[e] . Me[l][:,h]   (both layers in one eattr pass)
__global__ void trg_ae(const float* __restrict__ eattr, const float* __restrict__ Me,
                       float* __restrict__ AE) {
  __shared__ float sE[32 * 129];
  __shared__ float sM[128 * 8];
  int t = threadIdx.x;
  int e0 = blockIdx.x * 32;
  int el = t & 31, og = t >> 5;   // og = l*4+h
  float acc = 0.f;
  for (int kc = 0; kc < 6; kc++) {
    __syncthreads();
    for (int idx = t; idx < 32 * 128; idx += 256) {
      int row = idx >> 7, col = idx & 127;
      sE[row * 129 + col] = eattr[(long)(e0 + row) * EDD + kc * 128 + col];
    }
    for (int idx = t; idx < 128 * 8; idx += 256) {
      int c = idx >> 3, o = idx & 7;
      int l = o >> 2, h = o & 3;
      sM[c * 8 + o] = Me[((long)l * EDD + kc * 128 + c) * 4 + h];
    }
    __syncthreads();
#pragma unroll 8
    for (int c = 0; c < 128; c++)
      acc += sE[el * 129 + c] * sM[c * 8 + og];
  }
  AE[(long)(e0 + el) * 8 + og] = acc;
}

// ---------------- MFMA GEMM:  C = A[M,K](bf16) * B, B given as Bt[Nc,K](bf16) ----------------
// MODE 0: bf16 store (per-z batch). MODE 1: relu(acc+bias)->bf16. MODE 2: acc+bias+res -> f32.
template <int MODE>
__global__ void trg_gemm_bt(const __hip_bfloat16* __restrict__ A,
                            const __hip_bfloat16* __restrict__ Bt,
                            void* __restrict__ Cout,
                            const float* __restrict__ bias,
                            const float* __restrict__ res,
                            int M, int K, int Nc, long sB, long sC) {
  __shared__ __align__(16) unsigned short sAa[128 * 32];
  __shared__ __align__(16) unsigned short sBb[128 * 32];
  const int tid = threadIdx.x;
  const int lane = tid & 63;
  const int wave = tid >> 6;
  const int m0 = blockIdx.x * 128;
  const int n0 = blockIdx.y * 128;
  const __hip_bfloat16* Bz = Bt + (long)blockIdx.z * sB;
  const int wm = (wave >> 1) * 64;
  const int wn = (wave & 1) * 64;
  const int r0 = tid >> 2;
  const int c0 = (tid & 3) * 8;
  const int lrow = lane & 15;
  const int lk = (lane >> 4) * 8;

  int ra = m0 + r0;      if (ra >= M) ra = M - 1;
  int rb = m0 + r0 + 64; if (rb >= M) rb = M - 1;
  const __hip_bfloat16* pa0 = A + (long)ra * K + c0;
  const __hip_bfloat16* pa1 = A + (long)rb * K + c0;
  const __hip_bfloat16* pb0 = Bz + (long)(n0 + r0) * K + c0;
  const __hip_bfloat16* pb1 = Bz + (long)(n0 + r0 + 64) * K + c0;

  f32x4 acc[4][4];
#pragma unroll
  for (int i = 0; i < 4; i++)
#pragma unroll
    for (int j = 0; j < 4; j++) { f32x4 z = {0.f, 0.f, 0.f, 0.f}; acc[i][j] = z; }

  for (int kb = 0; kb < K; kb += 32) {
    uint4 va0 = *(const uint4*)(pa0 + kb);
    uint4 va1 = *(const uint4*)(pa1 + kb);
    uint4 vb0 = *(const uint4*)(pb0 + kb);
    uint4 vb1 = *(const uint4*)(pb1 + kb);
    __syncthreads();
    *(uint4*)(sAa + r0 * 32 + c0) = va0;
    *(uint4*)(sAa + (r0 + 64) * 32 + c0) = va1;
    *(uint4*)(sBb + r0 * 32 + c0) = vb0;
    *(uint4*)(sBb + (r0 + 64) * 32 + c0) = vb1;
    __syncthreads();
    bf16x8 af[4], bfr[4];
#pragma unroll
    for (int i = 0; i < 4; i++)
      af[i] = *(const bf16x8*)(sAa + (wm + i * 16 + lrow) * 32 + lk);
#pragma unroll
    for (int j = 0; j < 4; j++)
      bfr[j] = *(const bf16x8*)(sBb + (wn + j * 16 + lrow) * 32 + lk);
#pragma unroll
    for (int i = 0; i < 4; i++)
#pragma unroll
      for (int j = 0; j < 4; j++)
        acc[i][j] = __builtin_amdgcn_mfma_f32_16x16x32_bf16(af[i], bfr[j], acc[i][j], 0, 0, 0);
  }

  const int crow = (lane >> 4) * 4;
  const int ccol = lane & 15;
#pragma unroll
  for (int i = 0; i < 4; i++) {
#pragma unroll
    for (int j = 0; j < 4; j++) {
      int col = n0 + wn + j * 16 + ccol;
#pragma unroll
      for (int rg = 0; rg < 4; rg++) {
        int row = m0 + wm + i * 16 + crow + rg;
        if (row < M) {
          float v = acc[i][j][rg];
          if (MODE == 1) { v += bias[col]; v = v > 0.f ? v : 0.f; }
          if (MODE == 2) {
            v += bias[col] + res[(long)row * Nc + col];
            ((float*)Cout)[(long)row * Nc + col] = v;
          } else {
            (((__hip_bfloat16*)Cout) + (long)blockIdx.z * sC)[(long)row * Nc + col] =
                __float2bfloat16(v);
          }
        }
      }
    }
  }
}

// ---------------- attention pieces ----------------
// xwqk[row][o] = sum_c xwb[row][c] * qcat_l[c][o]   (row = r*NN+n, o: 0-3 q, 4-7 k)
__global__ void trg_xwqk(const __hip_bfloat16* __restrict__ xwb, const float* __restrict__ qcat_l,
                         float* __restrict__ xwqk) {
  __shared__ float sq[CC * 8];
  for (int i = threadIdx.x; i < CC * 8; i += 256) sq[i] = qcat_l[i];
  __syncthreads();
  int row = blockIdx.x * 32 + (threadIdx.x >> 3);
  int o = threadIdx.x & 7;
  const __hip_bfloat16* ar = xwb + (long)row * CC;
  float acc = 0.f;
  for (int c = 0; c < CC; c++) acc += __bfloat162float(ar[c]) * sq[c * 8 + o];
  xwqk[(long)row * 8 + o] = acc;
}

__global__ void trg_alpha(const int* __restrict__ ei, const int* __restrict__ et,
                          const float* __restrict__ xwqk, const float* __restrict__ AE,
                          float* __restrict__ alpha, int l) {
  int e = blockIdx.x * 256 + threadIdx.x;
  if (e >= EE) return;
  int s = ei[e], d = ei[EE + e], r = et[e];
  const float* qd = xwqk + ((long)r * NN + d) * 8;
  const float* ks = xwqk + ((long)r * NN + s) * 8;
  const float* ae = AE + (long)e * 8 + l * 4;
  float4 o;
  float a;
  a = qd[0] + ks[4] + ae[0]; o.x = a > 0.f ? a : 0.2f * a;
  a = qd[1] + ks[5] + ae[1]; o.y = a > 0.f ? a : 0.2f * a;
  a = qd[2] + ks[6] + ae[2]; o.z = a > 0.f ? a : 0.2f * a;
  a = qd[3] + ks[7] + ae[3]; o.w = a > 0.f ? a : 0.2f * a;
  *(float4*)(alpha + (long)e * 4) = o;
}

__global__ void trg_softmax(const int* __restrict__ offs, const int* __restrict__ elist,
                            float* __restrict__ alpha) {
  int idx = blockIdx.x * 256 + threadIdx.x;
  if (idx >= NN * HH) return;
  int n = idx >> 2, h = idx & 3;
  int beg = offs[n], end = offs[n + 1];
  float m = -1e30f;
  for (int i = beg; i < end; i++) m = fmaxf(m, alpha[(long)elist[i] * 4 + h]);
  float ssum = 0.f;
  for (int i = beg; i < end; i++) ssum += expf(alpha[(long)elist[i] * 4 + h] - m);
  float inv = 1.f / (ssum + 1e-16f);
  for (int i = beg; i < end; i++) {
    long a = (long)elist[i] * 4 + h;
    alpha[a] = expf(alpha[a] - m) * inv;
  }
}

// out[n] = sum_edges alpha * xwb[src under rel] + conv_bias + x_cur[n]  (in-place x update)
__global__ void trg_agg(const int* __restrict__ offs, const int* __restrict__ elist,
                        const int* __restrict__ ei, const int* __restrict__ et,
                        const float* __restrict__ alpha, const __hip_bfloat16* __restrict__ xwb,
                        const float* __restrict__ bias_l, float* __restrict__ x_cur) {
  int n = blockIdx.x;
  int t = threadIdx.x;
  int c0 = t, c1 = t + 256;
  int h0 = c0 >> 7, h1 = c1 >> 7;
  float a0 = 0.f, a1 = 0.f;
  int beg = offs[n], end = offs[n + 1];
  for (int i = beg; i < end; i++) {
    int e = elist[i];
    int s = ei[e];
    int r = et[e];
    long base = ((long)r * NN + s) * CC;
    float w0 = alpha[(long)e * 4 + h0];
    float w1 = alpha[(long)e * 4 + h1];
    a0 += w0 * __bfloat162float(xwb[base + c0]);
    a1 += w1 * __bfloat162float(xwb[base + c1]);
  }
  long xb = (long)n * CC;
  x_cur[xb + c0] = a0 + bias_l[c0] + x_cur[xb + c0];
  x_cur[xb + c1] = a1 + bias_l[c1] + x_cur[xb + c1];
}

// ---------------- LayerNorm ----------------
__device__ __forceinline__ float trg_blk_sum(float v, float* sb) {
#pragma unroll
  for (int o = 32; o > 0; o >>= 1) v += __shfl_down(v, o, 64);
  __syncthreads();
  if ((threadIdx.x & 63) == 0) sb[threadIdx.x >> 6] = v;
  __syncthreads();
  return sb[0] + sb[1] + sb[2] + sb[3];
}

__global__ void trg_ln1(const float* __restrict__ xc, const float* __restrict__ enc,
                        const float* __restrict__ g, const float* __restrict__ b,
                        float* __restrict__ xlnf, __hip_bfloat16* __restrict__ xlnb) {
  __shared__ float sb[4];
  int n = blockIdx.x, t = threadIdx.x;
  long base = (long)n * CC;
  float v0 = xc[base + t] + enc[base + t];
  float v1 = xc[base + t + 256] + enc[base + t + 256];
  float s = trg_blk_sum(v0 + v1, sb);
  float m = s * (1.f / CC);
  float d0 = v0 - m, d1 = v1 - m;
  float ss = trg_blk_sum(d0 * d0 + d1 * d1, sb);
  float rstd = rsqrtf(ss * (1.f / CC) + 1e-5f);
  float o0 = g[t] * d0 * rstd + b[t];
  float o1 = g[t + 256] * d1 * rstd + b[t + 256];
  xlnf[base + t] = o0;
  xlnf[base + t + 256] = o1;
  xlnb[base + t] = __float2bfloat16(o0);
  xlnb[base + t + 256] = __float2bfloat16(o1);
}

__global__ void trg_ln2(const float* __restrict__ y, const float* __restrict__ enc,
                        const float* __restrict__ g, const float* __restrict__ b,
                        float* __restrict__ out) {
  __shared__ float sb[4];
  int n = blockIdx.x, t = threadIdx.x;
  long base = (long)n * CC;
  float v0 = y[base + t], v1 = y[base + t + 256];
  float s = trg_blk_sum(v0 + v1, sb);
  float m = s * (1.f / CC);
  float d0 = v0 - m, d1 = v1 - m;
  float ss = trg_blk_sum(d0 * d0 + d1 * d1, sb);
  float rstd = rsqrtf(ss * (1.f / CC) + 1e-5f);
  out[base + t] = g[t] * d0 * rstd + b[t] + enc[base + t];
  out[base + t + 256] = g[t + 256] * d1 * rstd + b[t + 256] + enc[base + t + 256];
}

// ---------------- host ----------------
extern "C" void kernel_launch(void* const* d_in, const int* in_sizes, int n_in,
                              void* d_out, int out_size, void* d_ws, size_t ws_size,
                              hipStream_t stream) {
  const float* x_in   = (const float*)d_in[0];
  const int*   ei     = (const int*)d_in[1];
  const int*   et     = (const int*)d_in[2];
  const float* eattr  = (const float*)d_in[3];
  const float* weight = (const float*)d_in[4];
  const float* q_in   = (const float*)d_in[5];
  const float* k_in   = (const float*)d_in[6];
  const float* e_in   = (const float*)d_in[7];
  const float* w_edge = (const float*)d_in[8];
  const float* cbias  = (const float*)d_in[9];
  const float* ln_g   = (const float*)d_in[10];
  const float* ln_b   = (const float*)d_in[11];
  const float* ff1w   = (const float*)d_in[12];
  const float* ff1b   = (const float*)d_in[13];
  const float* ff2w   = (const float*)d_in[14];
  const float* ff2b   = (const float*)d_in[15];
  float* out = (float*)d_out;

  char* p = (char*)d_ws;
  auto alloc = [&](size_t bytes) {
    char* r = p;
    p += (bytes + 255) & ~(size_t)255;
    return r;
  };
  __hip_bfloat16* xwb   = (__hip_bfloat16*)alloc((size_t)RR * NN * CC * 2);
  __hip_bfloat16* x_bf  = (__hip_bfloat16*)alloc((size_t)NN * CC * 2);
  __hip_bfloat16* Wt_b  = (__hip_bfloat16*)alloc((size_t)LL * RR * CC * CC * 2);
  __hip_bfloat16* ff1t  = (__hip_bfloat16*)alloc((size_t)2 * CC * CC * 2);
  __hip_bfloat16* ff2t  = (__hip_bfloat16*)alloc((size_t)2 * CC * CC * 2);
  float* qcat  = (float*)alloc((size_t)LL * CC * 8 * 4);
  float* Me    = (float*)alloc((size_t)LL * EDD * HH * 4);
  float* AE    = (float*)alloc((size_t)EE * 8 * 4);
  float* xwqk  = (float*)alloc((size_t)RR * NN * 8 * 4);
  float* alpha = (float*)alloc((size_t)EE * 4 * 4);
  int* deg     = (int*)alloc((size_t)(NN + 1) * 4);
  int* offs    = (int*)alloc((size_t)(NN + 1) * 4);
  int* cursor  = (int*)alloc((size_t)(NN + 1) * 4);
  int* elist   = (int*)alloc((size_t)EE * 4);
  float* x_cur = (float*)alloc((size_t)NN * CC * 4);
  float* xln   = (float*)alloc((size_t)NN * CC * 4);
  __hip_bfloat16* xln_bf = (__hip_bfloat16*)alloc((size_t)NN * CC * 2);
  __hip_bfloat16* h_bf   = (__hip_bfloat16*)alloc((size_t)NN * 2 * CC * 2);
  float* y_tmp = (float*)alloc((size_t)NN * CC * 4);

  // phase 0: setup
  hipMemcpyAsync(x_cur, x_in, (size_t)NN * CC * 4, hipMemcpyDeviceToDevice, stream);
  hipMemsetAsync(deg, 0, (NN + 1) * 4, stream);
  trg_hist<<<EE / 256, 256, 0, stream>>>(ei, deg);
  trg_scan<<<1, 256, 0, stream>>>(deg, offs, cursor);
  trg_fill<<<EE / 256, 256, 0, stream>>>(ei, cursor, elist);

  dim3 tb(32, 8);
  trg_transpose<<<dim3(CC / 32, CC / 32, LL * RR), tb, 0, stream>>>(
      weight, Wt_b, CC, CC, (long)CC * CC, (long)CC * CC);
  trg_transpose<<<dim3(2 * CC / 32, CC / 32, 1), tb, 0, stream>>>(
      ff1w, ff1t, CC, 2 * CC, 0, 0);
  trg_transpose<<<dim3(CC / 32, 2 * CC / 32, 1), tb, 0, stream>>>(
      ff2w, ff2t, 2 * CC, CC, 0, 0);

  trg_me<<<(LL * EDD * HH + 255) / 256, 256, 0, stream>>>(w_edge, e_in, Me);
  trg_qcat<<<(LL * CC * 8 + 255) / 256, 256, 0, stream>>>(q_in, k_in, qcat);
  trg_ae<<<EE / 32, 256, 0, stream>>>(eattr, Me, AE);

  // layers
  for (int l = 0; l < LL; l++) {
    trg_cast_bf16<<<(NN * CC / 4 + 255) / 256, 256, 0, stream>>>(x_cur, x_bf, NN * CC / 4);
    trg_gemm_bt<0><<<dim3((NN + 127) / 128, CC / 128, RR), 256, 0, stream>>>(
        x_bf, Wt_b + (size_t)l * RR * CC * CC, xwb, nullptr, nullptr,
        NN, CC, CC, (long)CC * CC, (long)NN * CC);
    trg_xwqk<<<RR * NN / 32, 256, 0, stream>>>(xwb, qcat + (size_t)l * CC * 8, xwqk);
    trg_alpha<<<EE / 256, 256, 0, stream>>>(ei, et, xwqk, AE, alpha, l);
    trg_softmax<<<(NN * HH + 255) / 256, 256, 0, stream>>>(offs, elist, alpha);
    trg_agg<<<NN, 256, 0, stream>>>(offs, elist, ei, et, alpha, xwb,
                                    cbias + (size_t)l * CC, x_cur);
  }

  // head
  trg_ln1<<<NN, 256, 0, stream>>>(x_cur, x_in, ln_g, ln_b, xln, xln_bf);
  trg_gemm_bt<1><<<dim3((NN + 127) / 128, 2 * CC / 128, 1), 256, 0, stream>>>(
      xln_bf, ff1t, h_bf, ff1b, nullptr, NN, CC, 2 * CC, 0, 0);
  trg_gemm_bt<2><<<dim3((NN + 127) / 128, CC / 128, 1), 256, 0, stream>>>(
      h_bf, ff2t, y_tmp, ff2b, xln, NN, 2 * CC, CC, 0, 0);
  trg_ln2<<<NN, 256, 0, stream>>>(y_tmp, x_in, ln_g, ln_b, out);
}

// Round 2
// 1246.815 us; speedup vs baseline: 1.1259x; 1.1259x over previous
//
#include <hip/hip_runtime.h>
#include <hip/hip_bf16.h>

#define NN 10000
#define EE 160000
#define CC 512
#define HH 4
#define RR 8
#define LL 2
#define EDD 768
#define OO 128   // CC/HH

typedef __attribute__((ext_vector_type(8))) short bf16x8;
typedef __attribute__((ext_vector_type(4))) float f32x4;

typedef __attribute__((address_space(1))) const unsigned int as1cu;
typedef __attribute__((address_space(3))) unsigned int as3u;
__device__ __forceinline__ void gl2lds16(const void* g, void* l) {
  __builtin_amdgcn_global_load_lds((as1cu*)g, (as3u*)l, 16, 0, 0);
}

// ---------------- CSR build ----------------
__global__ void trg_hist(const int* __restrict__ ei, int* __restrict__ deg) {
  int e = blockIdx.x * 256 + threadIdx.x;
  if (e < EE) atomicAdd(&deg[ei[EE + e]], 1);
}

__global__ void trg_scan(const int* __restrict__ deg, int* __restrict__ offs,
                         int* __restrict__ cursor) {
  __shared__ int sp[256];
  int t = threadIdx.x;
  const int CHK = (NN + 255) / 256;
  int lo = t * CHK, hi = lo + CHK; if (hi > NN) hi = NN; if (lo > NN) lo = NN;
  int s = 0;
  for (int i = lo; i < hi; i++) s += deg[i];
  sp[t] = s;
  __syncthreads();
  if (t == 0) {
    int run = 0;
    for (int i = 0; i < 256; i++) { int v = sp[i]; sp[i] = run; run += v; }
  }
  __syncthreads();
  int run = sp[t];
  for (int i = lo; i < hi; i++) { offs[i] = run; cursor[i] = run; run += deg[i]; }
  if (t == 255) offs[NN] = run;
}

__global__ void trg_fill(const int* __restrict__ ei, int* __restrict__ cursor,
                         int* __restrict__ elist) {
  int e = blockIdx.x * 256 + threadIdx.x;
  if (e < EE) {
    int pos = atomicAdd(&cursor[ei[EE + e]], 1);
    elist[pos] = e;
  }
}

// ---------------- conversions ----------------
__global__ void trg_transpose(const float* __restrict__ in, __hip_bfloat16* __restrict__ out,
                              int P, int Q, long inStride, long outStride) {
  __shared__ float tile[32][33];
  int z = blockIdx.z;
  const float* inz = in + (long)z * inStride;
  __hip_bfloat16* outz = out + (long)z * outStride;
  int q0 = blockIdx.x * 32, p0 = blockIdx.y * 32;
  int tx = threadIdx.x, ty = threadIdx.y;
#pragma unroll
  for (int i = 0; i < 4; i++)
    tile[ty + i * 8][tx] = inz[(long)(p0 + ty + i * 8) * Q + q0 + tx];
  __syncthreads();
#pragma unroll
  for (int i = 0; i < 4; i++)
    outz[(long)(q0 + ty + i * 8) * P + p0 + tx] = __float2bfloat16(tile[tx][ty + i * 8]);
}

__global__ void trg_cast_bf16(const float* __restrict__ in, __hip_bfloat16* __restrict__ out, int n4) {
  int i = blockIdx.x * 256 + threadIdx.x;
  if (i >= n4) return;
  float4 v = ((const float4*)in)[i];
  union { ushort4 u; __hip_bfloat16 h[4]; } cv;
  cv.h[0] = __float2bfloat16(v.x); cv.h[1] = __float2bfloat16(v.y);
  cv.h[2] = __float2bfloat16(v.z); cv.h[3] = __float2bfloat16(v.w);
  ((ushort4*)out)[i] = cv.u;
}

// ---------------- small precomputes ----------------
// Me[l][ed][h] = sum_c w_edge[l][ed][c] * e[l][c][h]
__global__ void trg_me(const float* __restrict__ we, const float* __restrict__ ep,
                       float* __restrict__ Me) {
  int idx = blockIdx.x * 256 + threadIdx.x;
  if (idx >= LL * EDD * HH) return;
  int l = idx / (EDD * HH);
  int r = idx % (EDD * HH);
  int ed = r / HH, h = r % HH;
  const float* wr = we + ((long)l * EDD + ed) * CC;
  const float* ec = ep + (long)l * CC * HH + h;
  float acc = 0.f;
  for (int c = 0; c < CC; c++) acc += wr[c] * ec[c * HH];
  Me[idx] = acc;
}

// qcat[l][c][j]: j<4 -> q[l][c][j], else k[l][c][j-4]
__global__ void trg_qcat(const float* __restrict__ qp, const float* __restrict__ kp,
                         float* __restrict__ qcat) {
  int idx = blockIdx.x * 256 + threadIdx.x;
  if (idx >= LL * CC * 8) return;
  int l = idx / (CC * 8);
  int r = idx % (CC * 8);
  int c = r >> 3, j = r & 7;
  qcat[idx] = (j < 4) ? qp[((long)l * CC + c) * HH + j]
                      : kp[((long)l * CC + c) * HH + (j - 4)];
}

// Wqkt[l][(r*8+o)][c] = sum_d W[l][r][c][d] * qcat[l][d][o]  (bf16 out, B^T layout)
__global__ void trg_wqk(const float* __restrict__ W, const float* __restrict__ qcat,
                        __hip_bfloat16* __restrict__ Wqkt) {
  __shared__ float qs[CC * 8];
  int lr = blockIdx.y;          // l*8 + r
  int l = lr >> 3, r = lr & 7;
  int t = threadIdx.x;
  for (int i = t; i < CC * 8; i += 256) qs[i] = qcat[(long)l * CC * 8 + i];
  __syncthreads();
  int c = blockIdx.x * 128 + (t & 127);
  int oh = t >> 7;              // 0 or 1 -> outputs oh*4..oh*4+3
  const float4* Wrow = (const float4*)(W + ((long)lr * CC + c) * CC);
  float a0 = 0.f, a1 = 0.f, a2 = 0.f, a3 = 0.f;
  for (int d4 = 0; d4 < CC / 4; d4++) {
    float4 wv = Wrow[d4];
    const float* wp = &wv.x;
#pragma unroll
    for (int dd = 0; dd < 4; dd++) {
      float w = wp[dd];
      const float4 qv = *(const float4*)(qs + (d4 * 4 + dd) * 8 + oh * 4);
      a0 += w * qv.x; a1 += w * qv.y; a2 += w * qv.z; a3 += w * qv.w;
    }
  }
  long ob = ((long)l * 64 + r * 8 + oh * 4) * CC + c;
  Wqkt[ob] = __float2bfloat16(a0);
  Wqkt[ob + CC] = __float2bfloat16(a1);
  Wqkt[ob + 2 * CC] = __float2bfloat16(a2);
  Wqkt[ob + 3 * CC] = __float2bfloat16(a3);
}

// AE[e][l*4+h] = eattr[e] . Me[l][:,h]
__global__ void trg_ae(const float* __restrict__ eattr, const float* __restrict__ Me,
                       float* __restrict__ AE) {
  __shared__ float sE[32 * 132];
  __shared__ float sM[8 * 132];
  int t = threadIdx.x;
  int e0 = blockIdx.x * 32;
  int el = t >> 3, og = t & 7;
  float acc = 0.f;
  for (int kc = 0; kc < 6; kc++) {
    __syncthreads();
    for (int idx = t; idx < 1024; idx += 256) {
      int row = idx >> 5, c4 = idx & 31;
      *(float4*)(sE + row * 132 + c4 * 4) =
          *(const float4*)(eattr + (long)(e0 + row) * EDD + kc * 128 + c4 * 4);
    }
    for (int idx = t; idx < 1024; idx += 256) {
      int o = idx >> 7, c = idx & 127;
      sM[o * 132 + c] = Me[((long)(o >> 2) * EDD + kc * 128 + c) * 4 + (o & 3)];
    }
    __syncthreads();
#pragma unroll
    for (int c4 = 0; c4 < 32; c4++) {
      float4 ev = *(const float4*)(sE + el * 132 + c4 * 4);
      float4 mv = *(const float4*)(sM + og * 132 + c4 * 4);
      acc += ev.x * mv.x + ev.y * mv.y + ev.z * mv.z + ev.w * mv.w;
    }
  }
  AE[(long)(e0 + el) * 8 + og] = acc;
}

// ---------------- MFMA GEMM (128x128 tile, global_load_lds staging) ----------------
// MODE 0: bf16 store (per-z batch). MODE 1: relu(acc+bias)->bf16. MODE 2: acc+bias+res -> f32.
template <int MODE>
__global__ void trg_gemm_bt(const __hip_bfloat16* __restrict__ A,
                            const __hip_bfloat16* __restrict__ Bt,
                            void* __restrict__ Cout,
                            const float* __restrict__ bias,
                            const float* __restrict__ res,
                            int M, int K, int Nc, long sB, long sC) {
  __shared__ __align__(16) unsigned short sAa[128 * 32];
  __shared__ __align__(16) unsigned short sBb[128 * 32];
  const int tid = threadIdx.x;
  const int lane = tid & 63;
  const int wave = tid >> 6;
  const int m0 = blockIdx.x * 128;
  const int n0 = blockIdx.y * 128;
  const __hip_bfloat16* Bz = Bt + (long)blockIdx.z * sB;
  const int wm = (wave >> 1) * 64;
  const int wn = (wave & 1) * 64;
  const int lrow = lane & 15;
  const int lk = (lane >> 4) * 8;

  // staging coords: wave covers 16 rows (4 lanes/row, 8 shorts each)
  const int srow = wave * 16 + (lane >> 2);
  const int scol = (lane & 3) * 8;
  int ra = m0 + srow;      if (ra >= M) ra = M - 1;
  int rb = m0 + srow + 64; if (rb >= M) rb = M - 1;
  const __hip_bfloat16* pa0 = A + (long)ra * K + scol;
  const __hip_bfloat16* pa1 = A + (long)rb * K + scol;
  const __hip_bfloat16* pb0 = Bz + (long)(n0 + srow) * K + scol;
  const __hip_bfloat16* pb1 = Bz + (long)(n0 + srow + 64) * K + scol;
  unsigned short* la0 = sAa + wave * 512;
  unsigned short* la1 = sAa + 64 * 32 + wave * 512;
  unsigned short* lb0 = sBb + wave * 512;
  unsigned short* lb1 = sBb + 64 * 32 + wave * 512;

  f32x4 acc[4][4];
#pragma unroll
  for (int i = 0; i < 4; i++)
#pragma unroll
    for (int j = 0; j < 4; j++) { f32x4 z = {0.f, 0.f, 0.f, 0.f}; acc[i][j] = z; }

  for (int kb = 0; kb < K; kb += 32) {
    __syncthreads();
    gl2lds16(pa0 + kb, la0);
    gl2lds16(pa1 + kb, la1);
    gl2lds16(pb0 + kb, lb0);
    gl2lds16(pb1 + kb, lb1);
    __syncthreads();
    bf16x8 af[4], bfr[4];
#pragma unroll
    for (int i = 0; i < 4; i++)
      af[i] = *(const bf16x8*)(sAa + (wm + i * 16 + lrow) * 32 + lk);
#pragma unroll
    for (int j = 0; j < 4; j++)
      bfr[j] = *(const bf16x8*)(sBb + (wn + j * 16 + lrow) * 32 + lk);
#pragma unroll
    for (int i = 0; i < 4; i++)
#pragma unroll
      for (int j = 0; j < 4; j++)
        acc[i][j] = __builtin_amdgcn_mfma_f32_16x16x32_bf16(af[i], bfr[j], acc[i][j], 0, 0, 0);
  }

  const int crow = (lane >> 4) * 4;
  const int ccol = lane & 15;
#pragma unroll
  for (int i = 0; i < 4; i++) {
#pragma unroll
    for (int j = 0; j < 4; j++) {
      int col = n0 + wn + j * 16 + ccol;
#pragma unroll
      for (int rg = 0; rg < 4; rg++) {
        int row = m0 + wm + i * 16 + crow + rg;
        if (row < M) {
          float v = acc[i][j][rg];
          if (MODE == 1) { v += bias[col]; v = v > 0.f ? v : 0.f; }
          if (MODE == 2) {
            v += bias[col] + res[(long)row * Nc + col];
            ((float*)Cout)[(long)row * Nc + col] = v;
          } else {
            (((__hip_bfloat16*)Cout) + (long)blockIdx.z * sC)[(long)row * Nc + col] =
                __float2bfloat16(v);
          }
        }
      }
    }
  }
}

// small-N GEMM: C[M,64] f32 = A[M,512](bf16) @ Bt[64,512](bf16)^T
__global__ void trg_gemm_n64(const __hip_bfloat16* __restrict__ A,
                             const __hip_bfloat16* __restrict__ Bt,
                             float* __restrict__ Cout, int M) {
  __shared__ __align__(16) unsigned short sA[128 * 32];
  __shared__ __align__(16) unsigned short sB[64 * 32];
  const int tid = threadIdx.x;
  const int lane = tid & 63;
  const int wave = tid >> 6;
  const int m0 = blockIdx.x * 128;
  const int wm = wave * 32;
  const int lrow = lane & 15;
  const int lk = (lane >> 4) * 8;

  const int srow = wave * 16 + (lane >> 2);
  const int scol = (lane & 3) * 8;
  int ra = m0 + srow;      if (ra >= M) ra = M - 1;
  int rb = m0 + srow + 64; if (rb >= M) rb = M - 1;
  const __hip_bfloat16* pa0 = A + (long)ra * CC + scol;
  const __hip_bfloat16* pa1 = A + (long)rb * CC + scol;
  const __hip_bfloat16* pb = Bt + (long)srow * CC + scol;
  unsigned short* la0 = sA + wave * 512;
  unsigned short* la1 = sA + 64 * 32 + wave * 512;
  unsigned short* lb = sB + wave * 512;

  f32x4 acc[2][4];
#pragma unroll
  for (int i = 0; i < 2; i++)
#pragma unroll
    for (int j = 0; j < 4; j++) { f32x4 z = {0.f, 0.f, 0.f, 0.f}; acc[i][j] = z; }

  for (int kb = 0; kb < CC; kb += 32) {
    __syncthreads();
    gl2lds16(pa0 + kb, la0);
    gl2lds16(pa1 + kb, la1);
    gl2lds16(pb + kb, lb);
    __syncthreads();
    bf16x8 af[2], bfr[4];
#pragma unroll
    for (int i = 0; i < 2; i++)
      af[i] = *(const bf16x8*)(sA + (wm + i * 16 + lrow) * 32 + lk);
#pragma unroll
    for (int j = 0; j < 4; j++)
      bfr[j] = *(const bf16x8*)(sB + (j * 16 + lrow) * 32 + lk);
#pragma unroll
    for (int i = 0; i < 2; i++)
#pragma unroll
      for (int j = 0; j < 4; j++)
        acc[i][j] = __builtin_amdgcn_mfma_f32_16x16x32_bf16(af[i], bfr[j], acc[i][j], 0, 0, 0);
  }

  const int crow = (lane >> 4) * 4;
  const int ccol = lane & 15;
#pragma unroll
  for (int i = 0; i < 2; i++)
#pragma unroll
    for (int j = 0; j < 4; j++) {
      int col = j * 16 + ccol;
#pragma unroll
      for (int rg = 0; rg < 4; rg++) {
        int row = m0 + wm + i * 16 + crow + rg;
        if (row < M) Cout[(long)row * 64 + col] = acc[i][j][rg];
      }
    }
}

// ---------------- attention pieces ----------------
__global__ void trg_alpha(const int* __restrict__ ei, const int* __restrict__ et,
                          const float* __restrict__ xwqk, const float* __restrict__ AE,
                          float* __restrict__ alpha, int l) {
  int e = blockIdx.x * 256 + threadIdx.x;
  if (e >= EE) return;
  int s = ei[e], d = ei[EE + e], r = et[e];
  float4 qv = *(const float4*)(xwqk + (long)d * 64 + r * 8);
  float4 kv = *(const float4*)(xwqk + (long)s * 64 + r * 8 + 4);
  float4 ae = *(const float4*)(AE + (long)e * 8 + l * 4);
  float4 o;
  float a;
  a = qv.x + kv.x + ae.x; o.x = a > 0.f ? a : 0.2f * a;
  a = qv.y + kv.y + ae.y; o.y = a > 0.f ? a : 0.2f * a;
  a = qv.z + kv.z + ae.z; o.z = a > 0.f ? a : 0.2f * a;
  a = qv.w + kv.w + ae.w; o.w = a > 0.f ? a : 0.2f * a;
  *(float4*)(alpha + (long)e * 4) = o;
}

__global__ void trg_softmax(const int* __restrict__ offs, const int* __restrict__ elist,
                            float* __restrict__ alpha) {
  int idx = blockIdx.x * 256 + threadIdx.x;
  if (idx >= NN * HH) return;
  int n = idx >> 2, h = idx & 3;
  int beg = offs[n], end = offs[n + 1];
  float m = -1e30f;
  for (int i = beg; i < end; i++) m = fmaxf(m, alpha[(long)elist[i] * 4 + h]);
  float ssum = 0.f;
  for (int i = beg; i < end; i++) ssum += expf(alpha[(long)elist[i] * 4 + h] - m);
  float inv = 1.f / (ssum + 1e-16f);
  for (int i = beg; i < end; i++) {
    long a = (long)elist[i] * 4 + h;
    alpha[a] = expf(alpha[a] - m) * inv;
  }
}

// x_cur[n] += sum_edges alpha * xwb[src under rel] + conv_bias ; also emit bf16
__global__ void trg_agg(const int* __restrict__ offs, const int* __restrict__ elist,
                        const int* __restrict__ ei, const int* __restrict__ et,
                        const float* __restrict__ alpha, const __hip_bfloat16* __restrict__ xwb,
                        const float* __restrict__ bias_l, float* __restrict__ x_cur,
                        __hip_bfloat16* __restrict__ x_bf) {
  __shared__ float red[4][512];
  int n = blockIdx.x;
  int t = threadIdx.x;
  int wave = t >> 6, lane = t & 63;
  int c0 = lane * 8;
  int h = lane >> 4;
  float acc[8];
#pragma unroll
  for (int j = 0; j < 8; j++) acc[j] = 0.f;
  int beg = offs[n], end = offs[n + 1];
  for (int i = beg + wave; i < end; i += 4) {
    int e = elist[i];
    int s = ei[e], r = et[e];
    float w = alpha[(long)e * 4 + h];
    uint4 u = *(const uint4*)(xwb + ((long)r * NN + s) * CC + c0);
    acc[0] += w * __uint_as_float(u.x << 16);
    acc[1] += w * __uint_as_float(u.x & 0xffff0000u);
    acc[2] += w * __uint_as_float(u.y << 16);
    acc[3] += w * __uint_as_float(u.y & 0xffff0000u);
    acc[4] += w * __uint_as_float(u.z << 16);
    acc[5] += w * __uint_as_float(u.z & 0xffff0000u);
    acc[6] += w * __uint_as_float(u.w << 16);
    acc[7] += w * __uint_as_float(u.w & 0xffff0000u);
  }
#pragma unroll
  for (int j = 0; j < 8; j++) red[wave][c0 + j] = acc[j];
  __syncthreads();
  long xb = (long)n * CC;
  for (int c = t; c < CC; c += 256) {
    float v = red[0][c] + red[1][c] + red[2][c] + red[3][c] + bias_l[c] + x_cur[xb + c];
    x_cur[xb + c] = v;
    x_bf[xb + c] = __float2bfloat16(v);
  }
}

// ---------------- LayerNorm ----------------
__device__ __forceinline__ float trg_blk_sum(float v, float* sb) {
#pragma unroll
  for (int o = 32; o > 0; o >>= 1) v += __shfl_down(v, o, 64);
  __syncthreads();
  if ((threadIdx.x & 63) == 0) sb[threadIdx.x >> 6] = v;
  __syncthreads();
  return sb[0] + sb[1] + sb[2] + sb[3];
}

__global__ void trg_ln1(const float* __restrict__ xc, const float* __restrict__ enc,
                        const float* __restrict__ g, const float* __restrict__ b,
                        float* __restrict__ xlnf, __hip_bfloat16* __restrict__ xlnb) {
  __shared__ float sb[4];
  int n = blockIdx.x, t = threadIdx.x;
  long base = (long)n * CC;
  float v0 = xc[base + t] + enc[base + t];
  float v1 = xc[base + t + 256] + enc[base + t + 256];
  float s = trg_blk_sum(v0 + v1, sb);
  float m = s * (1.f / CC);
  float d0 = v0 - m, d1 = v1 - m;
  float ss = trg_blk_sum(d0 * d0 + d1 * d1, sb);
  float rstd = rsqrtf(ss * (1.f / CC) + 1e-5f);
  float o0 = g[t] * d0 * rstd + b[t];
  float o1 = g[t + 256] * d1 * rstd + b[t + 256];
  xlnf[base + t] = o0;
  xlnf[base + t + 256] = o1;
  xlnb[base + t] = __float2bfloat16(o0);
  xlnb[base + t + 256] = __float2bfloat16(o1);
}

__global__ void trg_ln2(const float* __restrict__ y, const float* __restrict__ enc,
                        const float* __restrict__ g, const float* __restrict__ b,
                        float* __restrict__ out) {
  __shared__ float sb[4];
  int n = blockIdx.x, t = threadIdx.x;
  long base = (long)n * CC;
  float v0 = y[base + t], v1 = y[base + t + 256];
  float s = trg_blk_sum(v0 + v1, sb);
  float m = s * (1.f / CC);
  float d0 = v0 - m, d1 = v1 - m;
  float ss = trg_blk_sum(d0 * d0 + d1 * d1, sb);
  float rstd = rsqrtf(ss * (1.f / CC) + 1e-5f);
  out[base + t] = g[t] * d0 * rstd + b[t] + enc[base + t];
  out[base + t + 256] = g[t + 256] * d1 * rstd + b[t + 256] + enc[base + t + 256];
}

// ---------------- host ----------------
extern "C" void kernel_launch(void* const* d_in, const int* in_sizes, int n_in,
                              void* d_out, int out_size, void* d_ws, size_t ws_size,
                              hipStream_t stream) {
  const float* x_in   = (const float*)d_in[0];
  const int*   ei     = (const int*)d_in[1];
  const int*   et     = (const int*)d_in[2];
  const float* eattr  = (const float*)d_in[3];
  const float* weight = (const float*)d_in[4];
  const float* q_in   = (const float*)d_in[5];
  const float* k_in   = (const float*)d_in[6];
  const float* e_in   = (const float*)d_in[7];
  const float* w_edge = (const float*)d_in[8];
  const float* cbias  = (const float*)d_in[9];
  const float* ln_g   = (const float*)d_in[10];
  const float* ln_b   = (const float*)d_in[11];
  const float* ff1w   = (const float*)d_in[12];
  const float* ff1b   = (const float*)d_in[13];
  const float* ff2w   = (const float*)d_in[14];
  const float* ff2b   = (const float*)d_in[15];
  float* out = (float*)d_out;

  char* p = (char*)d_ws;
  auto alloc = [&](size_t bytes) {
    char* r = p;
    p += (bytes + 255) & ~(size_t)255;
    return r;
  };
  __hip_bfloat16* xwb   = (__hip_bfloat16*)alloc((size_t)RR * NN * CC * 2);
  __hip_bfloat16* x_bf  = (__hip_bfloat16*)alloc((size_t)NN * CC * 2);
  __hip_bfloat16* Wt_b  = (__hip_bfloat16*)alloc((size_t)LL * RR * CC * CC * 2);
  __hip_bfloat16* ff1t  = (__hip_bfloat16*)alloc((size_t)2 * CC * CC * 2);
  __hip_bfloat16* ff2t  = (__hip_bfloat16*)alloc((size_t)2 * CC * CC * 2);
  __hip_bfloat16* Wqkt  = (__hip_bfloat16*)alloc((size_t)LL * 64 * CC * 2);
  float* qcat  = (float*)alloc((size_t)LL * CC * 8 * 4);
  float* Me    = (float*)alloc((size_t)LL * EDD * HH * 4);
  float* AE    = (float*)alloc((size_t)EE * 8 * 4);
  float* xwqk  = (float*)alloc((size_t)NN * 64 * 4);
  float* alpha = (float*)alloc((size_t)EE * 4 * 4);
  int* deg     = (int*)alloc((size_t)(NN + 1) * 4);
  int* offs    = (int*)alloc((size_t)(NN + 1) * 4);
  int* cursor  = (int*)alloc((size_t)(NN + 1) * 4);
  int* elist   = (int*)alloc((size_t)EE * 4);
  float* x_cur = (float*)alloc((size_t)NN * CC * 4);
  float* xln   = (float*)alloc((size_t)NN * CC * 4);
  __hip_bfloat16* xln_bf = (__hip_bfloat16*)alloc((size_t)NN * CC * 2);
  __hip_bfloat16* h_bf   = (__hip_bfloat16*)alloc((size_t)NN * 2 * CC * 2);
  float* y_tmp = (float*)alloc((size_t)NN * CC * 4);

  // phase 0: setup
  hipMemcpyAsync(x_cur, x_in, (size_t)NN * CC * 4, hipMemcpyDeviceToDevice, stream);
  hipMemsetAsync(deg, 0, (NN + 1) * 4, stream);
  trg_hist<<<EE / 256, 256, 0, stream>>>(ei, deg);
  trg_scan<<<1, 256, 0, stream>>>(deg, offs, cursor);
  trg_fill<<<EE / 256, 256, 0, stream>>>(ei, cursor, elist);

  dim3 tb(32, 8);
  trg_transpose<<<dim3(CC / 32, CC / 32, LL * RR), tb, 0, stream>>>(
      weight, Wt_b, CC, CC, (long)CC * CC, (long)CC * CC);
  trg_transpose<<<dim3(2 * CC / 32, CC / 32, 1), tb, 0, stream>>>(
      ff1w, ff1t, CC, 2 * CC, 0, 0);
  trg_transpose<<<dim3(CC / 32, 2 * CC / 32, 1), tb, 0, stream>>>(
      ff2w, ff2t, 2 * CC, CC, 0, 0);

  trg_me<<<(LL * EDD * HH + 255) / 256, 256, 0, stream>>>(w_edge, e_in, Me);
  trg_qcat<<<(LL * CC * 8 + 255) / 256, 256, 0, stream>>>(q_in, k_in, qcat);
  trg_wqk<<<dim3(4, LL * RR), 256, 0, stream>>>(weight, qcat, Wqkt);
  trg_ae<<<EE / 32, 256, 0, stream>>>(eattr, Me, AE);
  trg_cast_bf16<<<(NN * CC / 4 + 255) / 256, 256, 0, stream>>>(x_cur, x_bf, NN * CC / 4);

  // layers
  for (int l = 0; l < LL; l++) {
    trg_gemm_bt<0><<<dim3((NN + 127) / 128, CC / 128, RR), 256, 0, stream>>>(
        x_bf, Wt_b + (size_t)l * RR * CC * CC, xwb, nullptr, nullptr,
        NN, CC, CC, (long)CC * CC, (long)NN * CC);
    trg_gemm_n64<<<(NN + 127) / 128, 256, 0, stream>>>(
        x_bf, Wqkt + (size_t)l * 64 * CC, xwqk, NN);
    trg_alpha<<<EE / 256, 256, 0, stream>>>(ei, et, xwqk, AE, alpha, l);
    trg_softmax<<<(NN * HH + 255) / 256, 256, 0, stream>>>(offs, elist, alpha);
    trg_agg<<<NN, 256, 0, stream>>>(offs, elist, ei, et, alpha, xwb,
                                    cbias + (size_t)l * CC, x_cur, x_bf);
  }

  // head
  trg_ln1<<<NN, 256, 0, stream>>>(x_cur, x_in, ln_g, ln_b, xln, xln_bf);
  trg_gemm_bt<1><<<dim3((NN + 127) / 128, 2 * CC / 128, 1), 256, 0, stream>>>(
      xln_bf, ff1t, h_bf, ff1b, nullptr, NN, CC, 2 * CC, 0, 0);
  trg_gemm_bt<2><<<dim3((NN + 127) / 128, CC / 128, 1), 256, 0, stream>>>(
      h_bf, ff2t, y_tmp, ff2b, xln, NN, 2 * CC, CC, 0, 0);
  trg_ln2<<<NN, 256, 0, stream>>>(y_tmp, x_in, ln_g, ln_b, out);
}